// Round 10
// baseline (258.380 us; speedup 1.0000x reference)
//
#include <hip/hip_runtime.h>
#include <stdint.h>

// Circular conv1d: x (B=64, C_in=8, L=65536) fp32, W (8,8,4), b (8,).
// Memory-bound, ~200MB HBM traffic -> ~32-35us floor.
// R9 (global_load_lds + dbuf + counted vmcnt) fixed the spill problem but
// had 2 bugs: (a) vmcnt(6) also waited for the 8 nt stores (vmcnt counts
// ALL VMEM ops) -> store ack latency on the critical path every iter, the
// prefetch never actually overlapped; (b) pp=tid*2 scalar LDS reads ->
// 4-way bank conflicts (2.16M cycles). This round fixes the counts and
// the layout:
//   queue at iter-i wait (oldest->newest): L_i(6), S_{i-1}(4), L_{i+1}(6)
//   -> steady-state s_waitcnt vmcnt(10) drains exactly L_i; stores and
//   next-tile loads stay in flight. Prologue vmcnt(6), epilogue vmcnt(4).
//   Compute: thread = (pos-quad tq=tid&127, co-group cg=tid>>7); reads
//   x[4*tq .. 4*tq+7] as two ds_read_b128 (conflict-free), computes 4
//   positions x 4 c_out, stores 4 float4 nt.
// 1024 blocks x 34KB LDS = exactly 4 blocks/CU resident (persistent).
#define CIN 8
#define COUT 8
#define LEN 65536
#define FS 4
#define TILE 512
#define CSTRIDE 516                       // 512 + 4 halo floats (16B-aligned)
#define NBLOCKS 1024
#define NTILES 8192                       // 64 batches * 128 tiles
#define ITERS (NTILES / NBLOCKS)          // 8

typedef float floatx4 __attribute__((ext_vector_type(4)));

#define GLOAD16(g, l)                                                        \
    __builtin_amdgcn_global_load_lds(                                        \
        (const __attribute__((address_space(1))) void*)(g),                  \
        (__attribute__((address_space(3))) void*)(l), 16, 0, 0)

#define WAITBAR(N)                                                           \
    asm volatile("s_waitcnt vmcnt(" #N ")\n\ts_barrier" ::: "memory")

__global__ __launch_bounds__(256)
__attribute__((amdgpu_waves_per_eu(4, 4)))
void conv_pbc_kernel(const float* __restrict__ x,
                     const float* __restrict__ W,
                     const float* __restrict__ bias,
                     float* __restrict__ out)
{
    __shared__ __align__(16) float sX[2][CIN * CSTRIDE];  // 2 x 16.1 KB
    __shared__ floatx4 sWv[COUT * CIN];                   // (co,ci) -> 4 taps
    __shared__ float   sB[COUT];

    const int tid  = threadIdx.x;
    const int wave = tid >> 6;
    const int lane = tid & 63;
    const int cg   = tid >> 7;        // co group (0: co 0-3, 1: co 4-7), wave-uniform
    const int tq   = tid & 127;       // position quad
    const int pp   = tq * 4;

    if (tid < COUT * CIN) sWv[tid] = *reinterpret_cast<const floatx4*>(W + tid * FS);
    if (tid < COUT)       sB[tid]  = bias[tid];
    __syncthreads();

    // Stage tile T into LDS buffer `dst`. Per wave: 4 main GLOAD16 + 2
    // single-lane halo GLOAD16 = 6 vmcnt entries, uniform across waves.
    auto stage = [&](float* dst, int T) {
        const int b  = T >> 7;                 // 128 tiles per batch row
        const int p0 = (T & 127) << 9;
        const float* xb = x + ((size_t)b << 19);
        const int c0 = wave * 2;
        const float* g0 = xb + ((size_t)c0 << 16) + p0;
        const float* g1 = xb + ((size_t)(c0 + 1) << 16) + p0;
        float* d0 = dst + c0 * CSTRIDE;
        float* d1 = dst + (c0 + 1) * CSTRIDE;
        GLOAD16(g0 + lane * 4,       d0);
        GLOAD16(g0 + 256 + lane * 4, d0 + 256);
        GLOAD16(g1 + lane * 4,       d1);
        GLOAD16(g1 + 256 + lane * 4, d1 + 256);
        const int hoff = (p0 + TILE) & (LEN - 1);   // circular halo
        if (lane == 0) {
            GLOAD16(xb + ((size_t)c0 << 16) + hoff,       d0 + TILE);
            GLOAD16(xb + ((size_t)(c0 + 1) << 16) + hoff, d1 + TILE);
        }
    };

    // Compute tile T from buffer `buf`; 4 positions x 4 c_out per thread.
    auto compute_store = [&](const float* buf, int T) {
        const int b  = T >> 7;
        const int p0 = (T & 127) << 9;

        float acc[4][4];
#pragma unroll
        for (int j = 0; j < 4; ++j) {
            const float bb = sB[cg * 4 + j];
            acc[j][0] = bb; acc[j][1] = bb; acc[j][2] = bb; acc[j][3] = bb;
        }

#pragma unroll
        for (int ci = 0; ci < CIN; ++ci) {
            const float* xc = buf + ci * CSTRIDE + pp;
            const floatx4 lo = *reinterpret_cast<const floatx4*>(xc);      // b128
            const floatx4 hi = *reinterpret_cast<const floatx4*>(xc + 4);  // b128
            const float x0 = lo.x, x1 = lo.y, x2 = lo.z, x3 = lo.w;
            const float x4 = hi.x, x5 = hi.y, x6 = hi.z;
#pragma unroll
            for (int j = 0; j < 4; ++j) {
                const floatx4 w = sWv[(cg * 4 + j) * CIN + ci];  // uniform
                acc[j][0] += w.x * x0 + w.y * x1 + w.z * x2 + w.w * x3;
                acc[j][1] += w.x * x1 + w.y * x2 + w.z * x3 + w.w * x4;
                acc[j][2] += w.x * x2 + w.y * x3 + w.z * x4 + w.w * x5;
                acc[j][3] += w.x * x3 + w.y * x4 + w.z * x5 + w.w * x6;
            }
        }

        float* ob = out + ((size_t)b << 19) + p0 + pp;
#pragma unroll
        for (int j = 0; j < 4; ++j) {
            const floatx4 v = {acc[j][0], acc[j][1], acc[j][2], acc[j][3]};
            __builtin_nontemporal_store(
                v, reinterpret_cast<floatx4*>(ob + ((size_t)(cg * 4 + j) << 16)));
        }
    };

    const int T0 = blockIdx.x;

    // ---- prologue: tiles 0 and 1 staged; compute tile 0 ----
    stage(sX[0], T0);                          // L_0
    stage(sX[1], T0 + NBLOCKS);                // L_1
    WAITBAR(6);                                // drain L_0; L_1 in flight
    compute_store(sX[0], T0);                  // S_0 (4 stores)
    asm volatile("s_barrier" ::: "memory");

    // ---- steady state: i = 1..6 ----
    float* cur = sX[1];
    float* nxt = sX[0];
    for (int i = 1; i < ITERS - 1; ++i) {
        stage(nxt, T0 + (i + 1) * NBLOCKS);    // L_{i+1}
        WAITBAR(10);                           // drain L_i; keep S_{i-1}+L_{i+1}
        compute_store(cur, T0 + i * NBLOCKS);  // S_i
        asm volatile("s_barrier" ::: "memory");
        float* t = cur; cur = nxt; nxt = t;
    }

    // ---- epilogue: tile 7 ----
    WAITBAR(4);                                // drain L_7; keep S_6
    compute_store(cur, T0 + (ITERS - 1) * NBLOCKS);
}

extern "C" void kernel_launch(void* const* d_in, const int* in_sizes, int n_in,
                              void* d_out, int out_size, void* d_ws, size_t ws_size,
                              hipStream_t stream) {
    const float* x    = (const float*)d_in[0];
    const float* W    = (const float*)d_in[1];
    const float* bias = (const float*)d_in[2];
    float* out = (float*)d_out;

    conv_pbc_kernel<<<dim3(NBLOCKS), dim3(256), 0, stream>>>(x, W, bias, out);
}